// Round 6
// baseline (326.420 us; speedup 1.0000x reference)
//
#include <hip/hip_runtime.h>
#include <stdint.h>

#define B_  4
#define S_  2048
#define C_  1024
#define NH_ 16
#define HD_ 64
#define M_  (B_*S_)   // 8192
#define NT_ (S_/64)   // 32 q/k tiles
#define NKT 16        // K=1024 / BK=64 K-tiles for all projections

typedef __attribute__((ext_vector_type(8))) short bf16x8;
typedef __attribute__((ext_vector_type(4))) float f32x4;

typedef __attribute__((address_space(1))) const unsigned int gu32;
typedef __attribute__((address_space(3))) unsigned int lu32;

__device__ __forceinline__ void gload16(const void* g, void* l) {
    __builtin_amdgcn_global_load_lds((gu32*)g, (lu32*)l, 16, 0, 0);
}

__device__ __forceinline__ unsigned short f2bf(float f) {
    union { float f; unsigned u; } v; v.f = f;
    unsigned r = v.u + 0x7FFF + ((v.u >> 16) & 1);   // RNE
    return (unsigned short)(r >> 16);
}

// ---------------- fused f32 -> bf16 convert (5 segments, 1 launch) ----------------
__global__ __launch_bounds__(256)
void cvt_all(const float4* __restrict__ x, const float4* __restrict__ y,
             const float4* __restrict__ wq, const float4* __restrict__ wkv,
             const float4* __restrict__ wo,
             uint4* __restrict__ xb, uint4* __restrict__ yb, uint4* __restrict__ wqb,
             uint4* __restrict__ wkvb, uint4* __restrict__ wob) {
    int i = blockIdx.x * 256 + threadIdx.x;
    const float4* src; uint4* dst; int off;
    if      (i < 1048576) { src = x;   dst = xb;   off = i; }
    else if (i < 2097152) { src = y;   dst = yb;   off = i - 1048576; }
    else if (i < 2228224) { src = wq;  dst = wqb;  off = i - 2097152; }
    else if (i < 2490368) { src = wkv; dst = wkvb; off = i - 2228224; }
    else                  { src = wo;  dst = wob;  off = i - 2490368; }
    float4 a = src[2*off], b = src[2*off+1];
    union { unsigned short s[8]; uint4 v; } u;
    u.s[0]=f2bf(a.x); u.s[1]=f2bf(a.y); u.s[2]=f2bf(a.z); u.s[3]=f2bf(a.w);
    u.s[4]=f2bf(b.x); u.s[5]=f2bf(b.y); u.s[6]=f2bf(b.z); u.s[7]=f2bf(b.w);
    dst[off] = u.v;
}

// =======================================================================
// v5 (resubmit after infra failure): m201-style 8-phase template at 256x256,
// BK=64, 8 waves (2M x 4N, wave-tile 128x64), 128 KiB dbuf LDS.
// Per phase: {ds_read subtile; stage 2 gloads; [lgkmcnt(8) if 12 reads];
//   barrier; lgkmcnt(0)+sched_barrier(0); setprio(1); 16 MFMA; setprio(0);
//   [counted vmcnt]; barrier; sched_barrier(0)}.
// Quadrants p0..p3 = (0,0),(0,1),(1,1),(1,0).
// Stage: p0->B0(t+1), p1->A1(t+1) [buf^1]; p2->A0(t+2), p3->B1(t+2) [cur,
// regions dead >=2 barriers earlier; reads retired via per-phase lgkmcnt(0)].
// Waits (gload units): end-p1 vmcnt(8) validates A1(t); end-p3 vmcnt(6)
// validates A0/B1/B0(t+1). Tails: kt=14 end-p3 vmcnt(2); kt=15 end-p1 vmcnt(0).
// Prologue: A0(0),B1(0),B0(0),A1(0),A0(1),B1(1); vmcnt(6).
// Swizzle (verified passing): LDS slot s of row r holds global chunk s^(r&7);
// read col = ((quad^(l16&7))<<3) ^ (ks*32).
// =======================================================================

#define STAGE_A(mi, kb, db) do { \
    gload16(gA + (size_t)(mi)*64*1024 + (kb),           sh + (db)*32768 + (w*8 + (mi)*64)*64); \
    gload16(gA + ((size_t)(mi)*64 + 128)*1024 + (kb),   sh + (db)*32768 + (w*8 + 128 + (mi)*64)*64); \
} while (0)

#define STAGE_B(ni, kb, db) do { \
    gload16(gB + (size_t)(ni)*32*1024 + (kb),           sh + (db)*32768 + 16384 + ((w>>2)*64 + (w&3)*8 + (ni)*32)*64); \
    gload16(gB + ((size_t)(ni)*32 + 128)*1024 + (kb),   sh + (db)*32768 + 16384 + ((w>>2)*64 + (w&3)*8 + (ni)*32 + 128)*64); \
} while (0)

#define READ_A(mi) do { \
    _Pragma("unroll") \
    for (int mf = 0; mf < 4; ++mf) { \
        int idx = (wy*128 + (mi)*64 + mf*16 + l16)*64 + colb; \
        af[mf][0] = *(const bf16x8*)&Asb[idx]; \
        af[mf][1] = *(const bf16x8*)&Asb[idx ^ 32]; \
    } \
} while (0)

#define READ_B(ni) do { \
    _Pragma("unroll") \
    for (int nf = 0; nf < 2; ++nf) { \
        int idx = (wx*64 + (ni)*32 + nf*16 + l16)*64 + colb; \
        bfv[ni][nf][0] = *(const bf16x8*)&Bsb[idx]; \
        bfv[ni][nf][1] = *(const bf16x8*)&Bsb[idx ^ 32]; \
    } \
} while (0)

#define MFMA_Q(mi, ni) do { \
    _Pragma("unroll") \
    for (int mf = 0; mf < 4; ++mf) { \
        _Pragma("unroll") \
        for (int nf = 0; nf < 2; ++nf) { \
            acc[mi][ni][mf][nf] = __builtin_amdgcn_mfma_f32_16x16x32_bf16(af[mf][0], bfv[ni][nf][0], acc[mi][ni][mf][nf], 0, 0, 0); \
            acc[mi][ni][mf][nf] = __builtin_amdgcn_mfma_f32_16x16x32_bf16(af[mf][1], bfv[ni][nf][1], acc[mi][ni][mf][nf], 0, 0, 0); \
        } \
    } \
} while (0)

// pre-MFMA: barrier, drain own LDS reads, pin the pure-MFMA cluster
#define PHASE_MID() do { \
    __builtin_amdgcn_s_barrier(); \
    asm volatile("s_waitcnt lgkmcnt(0)" ::: "memory"); \
    __builtin_amdgcn_sched_barrier(0); \
    __builtin_amdgcn_s_setprio(1); \
} while (0)

#define PHASE_END() do { \
    __builtin_amdgcn_s_barrier(); \
    __builtin_amdgcn_sched_barrier(0); \
} while (0)

template<int MODE>
__device__ __forceinline__
void gemm256_body(const unsigned short* __restrict__ A, const unsigned short* __restrict__ Bt,
                  const float* __restrict__ bias,
                  unsigned short* __restrict__ out0, unsigned short* __restrict__ out1,
                  float* __restrict__ outf, int bx, int by, unsigned short* sh)
{
    const int t = threadIdx.x;
    const int lane = t & 63, w = t >> 6;
    const int quad = lane >> 4, l16 = lane & 15;
    const int wy = w >> 2, wx = w & 3;
    const int s7 = l16 & 7;
    const int colb = (quad ^ s7) << 3;          // swizzled 16B slot (shorts)
    const int c16 = (lane & 7) ^ (lane >> 3);   // pre-swizzled source chunk

    const int rowA0 = by * 256;
    const int colB0 = bx * 256;

    const unsigned short* gA = A  + (size_t)(rowA0 + w*8 + (lane>>3))*1024 + c16*8;
    const unsigned short* gB = Bt + (size_t)(colB0 + (w>>2)*64 + (w&3)*8 + (lane>>3))*1024 + c16*8;

    f32x4 acc[2][2][4][2] = {};
    bf16x8 af[4][2], bfv[2][2][2];

    // ---- prologue: FIFO order A0(0),B1(0),B0(0),A1(0),A0(1),B1(1) ----
    STAGE_A(0, 0, 0);
    STAGE_B(1, 0, 0);
    STAGE_B(0, 0, 0);
    STAGE_A(1, 0, 0);
    STAGE_A(0, 64, 1);
    STAGE_B(1, 64, 1);
    asm volatile("s_waitcnt vmcnt(6)" ::: "memory");   // A0(0),B1(0),B0(0) landed
    __builtin_amdgcn_s_barrier();
    __builtin_amdgcn_sched_barrier(0);

    #pragma unroll 1
    for (int kt = 0; kt < NKT; ++kt) {
        const int cur = kt & 1;
        const unsigned short* Asb = sh + cur*32768;
        const unsigned short* Bsb = Asb + 16384;
        const int kb1 = (kt + 1) * 64;
        const int kb2 = (kt + 2) * 64;
        const bool st1 = (kt + 1 < NKT);
        const bool st2 = (kt + 2 < NKT);

        // ---- p0: quadrant (0,0); 12 ds_reads; stage B0(t+1) ----
        READ_A(0);
        READ_B(0);
        if (st1) STAGE_B(0, kb1, cur ^ 1);
        asm volatile("s_waitcnt lgkmcnt(8)" ::: "memory");   // throttle (12 reads)
        PHASE_MID();
        MFMA_Q(0, 0);
        __builtin_amdgcn_s_setprio(0);
        PHASE_END();

        // ---- p1: quadrant (0,1); 4 ds_reads; stage A1(t+1); vmcnt(8) ----
        READ_B(1);
        if (st1) STAGE_A(1, kb1, cur ^ 1);
        PHASE_MID();
        MFMA_Q(0, 1);
        __builtin_amdgcn_s_setprio(0);
        if (st1) asm volatile("s_waitcnt vmcnt(8)" ::: "memory");  // A1(kt) landed
        else     asm volatile("s_waitcnt vmcnt(0)" ::: "memory");
        PHASE_END();

        // ---- p2: quadrant (1,1); 8 ds_reads; stage A0(t+2) into cur ----
        READ_A(1);
        if (st2) STAGE_A(0, kb2, cur);
        PHASE_MID();
        MFMA_Q(1, 1);
        __builtin_amdgcn_s_setprio(0);
        PHASE_END();

        // ---- p3: quadrant (1,0); 0 ds_reads; stage B1(t+2) into cur; vmcnt(6) ----
        if (st2) STAGE_B(1, kb2, cur);
        __builtin_amdgcn_s_barrier();
        __builtin_amdgcn_sched_barrier(0);
        __builtin_amdgcn_s_setprio(1);
        MFMA_Q(1, 0);
        __builtin_amdgcn_s_setprio(0);
        if      (st2) asm volatile("s_waitcnt vmcnt(6)" ::: "memory");  // tile t+1 landed
        else if (st1) asm volatile("s_waitcnt vmcnt(2)" ::: "memory");  // kt==NKT-2
        PHASE_END();
    }

    // ---- epilogue ----
    const float QSCALE = 0.180336880111f;  // 0.125 * log2(e)
    #pragma unroll
    for (int mi = 0; mi < 2; ++mi)
    #pragma unroll
    for (int ni = 0; ni < 2; ++ni)
    #pragma unroll
    for (int nf = 0; nf < 2; ++nf) {
        int gn = colB0 + wx*64 + ni*32 + nf*16 + l16;
        float bv = bias[gn];
        #pragma unroll
        for (int mf = 0; mf < 4; ++mf) {
            #pragma unroll
            for (int r = 0; r < 4; ++r) {
                int gm = rowA0 + wy*128 + mi*64 + mf*16 + quad*4 + r;
                float v = acc[mi][ni][mf][nf][r] + bv;
                if (MODE == 2) {
                    outf[(size_t)gm * 1024 + gn] = v;
                } else if (MODE == 0) {
                    v *= QSCALE;
                    int b = gm >> 11, s = gm & 2047;
                    int h = gn >> 6,  d = gn & 63;
                    out0[(((size_t)(b*NH_ + h)*S_ + s) << 6) + d] = f2bf(v);
                } else {
                    int b = gm >> 11, s = gm & 2047;
                    if (gn < C_) {
                        int h = gn >> 6, d = gn & 63;
                        out0[(((size_t)(b*NH_ + h)*S_ + s) << 6) + d] = f2bf(v);
                    } else {
                        int n2 = gn - C_;
                        int h = n2 >> 6, d = n2 & 63;
                        out1[((size_t)(b*NH_ + h)*HD_ + d)*S_ + s] = f2bf(v);
                    }
                }
            }
        }
    }
}

// ---- fused Q-proj + KV-proj: 384 tiles (Q 128 + KV 256), XCD-chunked 8x48 ----
__global__ __launch_bounds__(512, 2)
void proj_fused256(const unsigned short* __restrict__ xb, const unsigned short* __restrict__ Wqb,
                   const float* __restrict__ Wq_b,
                   const unsigned short* __restrict__ yb, const unsigned short* __restrict__ Wkvb,
                   const float* __restrict__ Wkv_b,
                   unsigned short* __restrict__ Qg, unsigned short* __restrict__ Kg,
                   unsigned short* __restrict__ Vt)
{
    extern __shared__ unsigned short sh[];
    int bid = blockIdx.x;
    int id = (bid & 7) * 48 + (bid >> 3);   // XCD c gets ids [c*48, c*48+48)
    if (id < 128) {
        gemm256_body<0>(xb, Wqb, Wq_b, Qg, nullptr, nullptr, id & 3, id >> 2, sh);
    } else {
        int j = id - 128;
        gemm256_body<1>(yb, Wkvb, Wkv_b, Kg, Vt, nullptr, j & 7, j >> 3, sh);
    }
}

// ---- standalone O-projection: 128 tiles, XCD-chunked 8x16 ----
__global__ __launch_bounds__(512, 2)
void gemm_oproj256(const unsigned short* __restrict__ A, const unsigned short* __restrict__ Bt,
                   const float* __restrict__ bias, float* __restrict__ outf)
{
    extern __shared__ unsigned short sh[];
    int id = ((blockIdx.x & 7) << 4) + (blockIdx.x >> 3);
    gemm256_body<2>(A, Bt, bias, nullptr, nullptr, outf, id & 3, id >> 2, sh);
}

// ---------------- Flash attention, v3.2 (unchanged) ----------------
__global__ __launch_bounds__(256, 4)
void attn_kernel(const unsigned short* __restrict__ Qg, const unsigned short* __restrict__ Kg,
                 const unsigned short* __restrict__ Vt, const unsigned char* __restrict__ maskp,
                 unsigned short* __restrict__ att)
{
    __shared__ unsigned short Pl[64*72];
    __shared__ float Lbuf[4][64];
    __shared__ float Linv[64];
    int t = threadIdx.x, lane = t & 63, w = t >> 6;
    int quad = lane >> 4, l16 = lane & 15;
    int bh = blockIdx.x, b = bh >> 4, h = bh & 15;
    int qi = blockIdx.y;

    const unsigned short* kbase = Kg + ((size_t)bh*S_ + w*16 + l16)*HD_ + quad*8;
    const unsigned short* vbase = Vt + ((size_t)bh*HD_ + w*16 + l16)*S_ + quad*8;
    int kp_row = w*16 + quad*4;   // lane's k-row base within a tile
    const unsigned char* mbase = maskp + (size_t)b*S_ + kp_row;

    for (int half = 0; half < 2; ++half) {
        int qt = half ? (NT_ - 1 - qi) : qi;

        bf16x8 qf[4][2];
        #pragma unroll
        for (int m = 0; m < 4; ++m) {
            const unsigned short* qp = Qg + ((size_t)bh*S_ + qt*64 + m*16 + l16)*HD_;
            qf[m][0] = *reinterpret_cast<const bf16x8*>(qp + quad*8);
            qf[m][1] = *reinterpret_cast<const bf16x8*>(qp + 32 + quad*8);
        }
        f32x4 oacc[4] = {};
        float lsum[4] = {0.f, 0.f, 0.f, 0.f};

        bf16x8 kc0 = *reinterpret_cast<const bf16x8*>(kbase);
        bf16x8 kc1 = *reinterpret_cast<const bf16x8*>(kbase + 32);

        for (int kt = 0; kt <= qt; ++kt) {
            int ktn = (kt < qt) ? kt + 1 : kt;
            const unsigned short* kpn = kbase + (size_t)ktn*64*HD_;
            bf16x8 kn0 = *reinterpret_cast<const bf16x8*>(kpn);
            bf16x8 kn1 = *reinterpret_cast<const bf16x8*>(kpn + 32);
            const unsigned short* vp = vbase + kt*64;
            bf16x8 vc0 = *reinterpret_cast<const bf16x8*>(vp);
            bf16x8 vc1 = *reinterpret_cast<const bf16x8*>(vp + 32);

            unsigned m4 = *reinterpret_cast<const unsigned*>(mbase + kt*64);

            f32x4 sacc[4];
            #pragma unroll
            for (int m = 0; m < 4; ++m) {
                sacc[m] = __builtin_amdgcn_mfma_f32_16x16x32_bf16(kc0, qf[m][0], f32x4{}, 0, 0, 0);
                sacc[m] = __builtin_amdgcn_mfma_f32_16x16x32_bf16(kc1, qf[m][1], sacc[m], 0, 0, 0);
            }

            bool diag = (kt == qt);
            #pragma unroll
            for (int m = 0; m < 4; ++m) {
                float p[4];
                if (diag) {
                    #pragma unroll
                    for (int r = 0; r < 4; ++r) {
                        float s = sacc[m][r];
                        if (kp_row + r > m*16 + l16) s = -1e30f;
                        p[r] = __builtin_amdgcn_exp2f(s);
                    }
                } else {
                    #pragma unroll
                    for (int r = 0; r < 4; ++r)
                        p[r] = __builtin_amdgcn_exp2f(sacc[m][r]);
                }
                if (m4) {
                    #pragma unroll
                    for (int r = 0; r < 4; ++r)
                        if ((m4 >> (8*r)) & 0xFFu) p[r] = 0.f;
                }
                lsum[m] += (p[0] + p[1]) + (p[2] + p[3]);
                unsigned a01 = __builtin_amdgcn_perm(__float_as_uint(p[1]), __float_as_uint(p[0]), 0x07060302u);
                unsigned a23 = __builtin_amdgcn_perm(__float_as_uint(p[3]), __float_as_uint(p[2]), 0x07060302u);
                *reinterpret_cast<uint2*>(&Pl[(m*16 + l16)*72 + w*16 + quad*4]) = make_uint2(a01, a23);
            }
            __syncthreads();
            #pragma unroll
            for (int m = 0; m < 4; ++m) {
                bf16x8 pf0 = *reinterpret_cast<const bf16x8*>(&Pl[(m*16 + l16)*72 + quad*8]);
                bf16x8 pf1 = *reinterpret_cast<const bf16x8*>(&Pl[(m*16 + l16)*72 + 32 + quad*8]);
                oacc[m] = __builtin_amdgcn_mfma_f32_16x16x32_bf16(pf0, vc0, oacc[m], 0, 0, 0);
                oacc[m] = __builtin_amdgcn_mfma_f32_16x16x32_bf16(pf1, vc1, oacc[m], 0, 0, 0);
            }
            __syncthreads();
            kc0 = kn0; kc1 = kn1;
        }

        #pragma unroll
        for (int m = 0; m < 4; ++m) {
            lsum[m] += __shfl_xor(lsum[m], 16, 64);
            lsum[m] += __shfl_xor(lsum[m], 32, 64);
            Lbuf[w][m*16 + l16] = lsum[m];
        }
        __syncthreads();
        int q64 = t & 63;
        Linv[q64] = 1.0f / (Lbuf[0][q64] + Lbuf[1][q64] + Lbuf[2][q64] + Lbuf[3][q64]);
        __syncthreads();
        #pragma unroll
        for (int m = 0; m < 4; ++m) {
            #pragma unroll
            for (int r = 0; r < 4; ++r) {
                float iv = Linv[m*16 + quad*4 + r];
                int q = qt*64 + m*16 + quad*4 + r;
                att[((size_t)(b*S_ + q))*C_ + h*HD_ + w*16 + l16] = f2bf(oacc[m][r] * iv);
            }
        }
        __syncthreads();
    }
}

// ---------------- launch ----------------
extern "C" void kernel_launch(void* const* d_in, const int* in_sizes, int n_in,
                              void* d_out, int out_size, void* d_ws, size_t ws_size,
                              hipStream_t stream) {
    const float* x     = (const float*)d_in[0];
    const float* y     = (const float*)d_in[1];
    const unsigned char* mask = (const unsigned char*)d_in[2];
    const float* Wq_w  = (const float*)d_in[3];
    const float* Wq_b  = (const float*)d_in[4];
    const float* Wkv_w = (const float*)d_in[5];
    const float* Wkv_b = (const float*)d_in[6];
    const float* Wo_w  = (const float*)d_in[7];
    const float* Wo_b  = (const float*)d_in[8];
    float* out = (float*)d_out;

    unsigned short* xb   = (unsigned short*)d_ws;
    unsigned short* yb   = xb   + (size_t)M_*C_;
    unsigned short* Wqb  = yb   + (size_t)M_*C_;
    unsigned short* Wkvb = Wqb  + (size_t)C_*C_;
    unsigned short* Wob  = Wkvb + (size_t)2*C_*C_;
    unsigned short* Qg   = Wob  + (size_t)C_*C_;
    unsigned short* Kg   = Qg   + (size_t)M_*C_;
    unsigned short* Vtg  = Kg   + (size_t)M_*C_;
    unsigned short* att  = xb;   // xb dead after Q proj

    static bool once = []() {
        hipFuncSetAttribute((const void*)proj_fused256, hipFuncAttributeMaxDynamicSharedMemorySize, 131072);
        hipFuncSetAttribute((const void*)gemm_oproj256, hipFuncAttributeMaxDynamicSharedMemorySize, 131072);
        return true;
    }();
    (void)once;

    cvt_all<<<10240, 256, 0, stream>>>((const float4*)x, (const float4*)y,
        (const float4*)Wq_w, (const float4*)Wkv_w, (const float4*)Wo_w,
        (uint4*)xb, (uint4*)yb, (uint4*)Wqb, (uint4*)Wkvb, (uint4*)Wob);

    proj_fused256<<<384, 512, 131072, stream>>>(xb, Wqb, Wq_b, yb, Wkvb, Wkv_b, Qg, Kg, Vtg);
    attn_kernel<<<dim3(B_*NH_, NT_/2), 256, 0, stream>>>(Qg, Kg, Vtg, mask, att);
    gemm_oproj256<<<128, 512, 131072, stream>>>(att, Wob, Wo_b, out);
}

// Round 7
// 304.959 us; speedup vs baseline: 1.0704x; 1.0704x over previous
//
#include <hip/hip_runtime.h>
#include <stdint.h>

#define B_  4
#define S_  2048
#define C_  1024
#define NH_ 16
#define HD_ 64
#define M_  (B_*S_)   // 8192
#define NT_ (S_/64)   // 32 q/k tiles
#define NKT 16        // K=1024 / BK=64 K-tiles for all projections

typedef __attribute__((ext_vector_type(8))) short bf16x8;
typedef __attribute__((ext_vector_type(4))) float f32x4;

typedef __attribute__((address_space(1))) const unsigned int gu32;
typedef __attribute__((address_space(3))) unsigned int lu32;

__device__ __forceinline__ void gload16(const void* g, void* l) {
    __builtin_amdgcn_global_load_lds((gu32*)g, (lu32*)l, 16, 0, 0);
}

__device__ __forceinline__ unsigned short f2bf(float f) {
    union { float f; unsigned u; } v; v.f = f;
    unsigned r = v.u + 0x7FFF + ((v.u >> 16) & 1);   // RNE
    return (unsigned short)(r >> 16);
}

// ---------------- fused f32 -> bf16 convert (5 segments, 1 launch) ----------------
__global__ __launch_bounds__(256)
void cvt_all(const float4* __restrict__ x, const float4* __restrict__ y,
             const float4* __restrict__ wq, const float4* __restrict__ wkv,
             const float4* __restrict__ wo,
             uint4* __restrict__ xb, uint4* __restrict__ yb, uint4* __restrict__ wqb,
             uint4* __restrict__ wkvb, uint4* __restrict__ wob) {
    int i = blockIdx.x * 256 + threadIdx.x;
    const float4* src; uint4* dst; int off;
    if      (i < 1048576) { src = x;   dst = xb;   off = i; }
    else if (i < 2097152) { src = y;   dst = yb;   off = i - 1048576; }
    else if (i < 2228224) { src = wq;  dst = wqb;  off = i - 2097152; }
    else if (i < 2490368) { src = wkv; dst = wkvb; off = i - 2228224; }
    else                  { src = wo;  dst = wob;  off = i - 2490368; }
    float4 a = src[2*off], b = src[2*off+1];
    union { unsigned short s[8]; uint4 v; } u;
    u.s[0]=f2bf(a.x); u.s[1]=f2bf(a.y); u.s[2]=f2bf(a.z); u.s[3]=f2bf(a.w);
    u.s[4]=f2bf(b.x); u.s[5]=f2bf(b.y); u.s[6]=f2bf(b.z); u.s[7]=f2bf(b.w);
    dst[off] = u.v;
}

// =======================================================================
// v6: m97 geometry + R4 swizzle + XCD grids + multi-block TLP.
// 128x128 tile, BK=64, 4 waves (2Mx2N, wave-tile 64x64), 32 KiB single-buf
// LDS, __launch_bounds__(256,3) -> ~3 blocks/CU resident. Simple schedule:
// {read frags -> MFMA (x2 k-halves); sync; stage next tile; sync}. The
// exposed staging latency is covered by co-resident blocks (m114 mechanism),
// not intra-block choreography (which rounds 1-6 showed cannot overlap at
// 1 block/CU).
// Swizzle (verified 0-conflict since R1): LDS chunk slot s of row r holds
// global chunk s^(r&7); stage rows == lane>>3 (mod 8); read col slot =
// (quad ^ (l16&7)), k-half via ^32 shorts.
// =======================================================================

#define STAGE_A(u, kb) gload16(gA + (size_t)(u)*8*1024 + (kb), shA + (w*32 + (u)*8)*64)
#define STAGE_B(u, kb) gload16(gB + (size_t)(u)*8*1024 + (kb), shB + (w*32 + (u)*8)*64)
#define STAGE_ALL(kb) do { \
    STAGE_A(0, kb); STAGE_A(1, kb); STAGE_A(2, kb); STAGE_A(3, kb); \
    STAGE_B(0, kb); STAGE_B(1, kb); STAGE_B(2, kb); STAGE_B(3, kb); \
} while (0)

#define READ_AB(h) do { \
    const int co = colb ^ ((h)*32); \
    _Pragma("unroll") \
    for (int mf = 0; mf < 4; ++mf) \
        af[mf] = *(const bf16x8*)&shA[(wy*64 + mf*16 + l16)*64 + co]; \
    _Pragma("unroll") \
    for (int nf = 0; nf < 4; ++nf) \
        bf[nf] = *(const bf16x8*)&shB[(wx*64 + nf*16 + l16)*64 + co]; \
} while (0)

#define MFMA16() do { \
    _Pragma("unroll") \
    for (int mf = 0; mf < 4; ++mf) \
        _Pragma("unroll") \
        for (int nf = 0; nf < 4; ++nf) \
            acc[mf][nf] = __builtin_amdgcn_mfma_f32_16x16x32_bf16(af[mf], bf[nf], acc[mf][nf], 0, 0, 0); \
} while (0)

template<int MODE>
__device__ __forceinline__
void gemm128_body(const unsigned short* __restrict__ A, const unsigned short* __restrict__ Bt,
                  const float* __restrict__ bias,
                  unsigned short* __restrict__ out0, unsigned short* __restrict__ out1,
                  float* __restrict__ outf, int bx, int by,
                  unsigned short* shA, unsigned short* shB)
{
    const int t = threadIdx.x;
    const int lane = t & 63, w = t >> 6;
    const int quad = lane >> 4, l16 = lane & 15;
    const int wy = w >> 1, wx = w & 1;          // 2 M-groups x 2 N-groups
    const int colb = (quad ^ (l16 & 7)) << 3;   // swizzled 16B slot (shorts)
    const int c16 = (lane & 7) ^ (lane >> 3);   // pre-swizzled source chunk

    const int rowA0 = by * 128;
    const int colB0 = bx * 128;

    // per-lane staging bases: wave w covers rows w*32+[0,32) in 4 units of 8
    const unsigned short* gA = A  + (size_t)(rowA0 + w*32 + (lane>>3))*1024 + c16*8;
    const unsigned short* gB = Bt + (size_t)(colB0 + w*32 + (lane>>3))*1024 + c16*8;

    f32x4 acc[4][4] = {};
    bf16x8 af[4], bf[4];

    STAGE_ALL(0);
    __syncthreads();                      // drains vmcnt -> tile 0 visible

    #pragma unroll 1
    for (int kt = 0; kt < NKT; ++kt) {
        READ_AB(0);
        MFMA16();
        READ_AB(1);
        MFMA16();
        __syncthreads();                  // all waves' reads retired
        if (kt + 1 < NKT) STAGE_ALL((kt + 1) * 64);
        __syncthreads();                  // drains vmcnt -> next tile visible
    }

    // ---- epilogue ----
    const float QSCALE = 0.180336880111f;  // 0.125 * log2(e)
    #pragma unroll
    for (int nf = 0; nf < 4; ++nf) {
        int gn = colB0 + wx*64 + nf*16 + l16;
        float bv = bias[gn];
        #pragma unroll
        for (int mf = 0; mf < 4; ++mf) {
            #pragma unroll
            for (int r = 0; r < 4; ++r) {
                int gm = rowA0 + wy*64 + mf*16 + quad*4 + r;
                float v = acc[mf][nf][r] + bv;
                if (MODE == 2) {
                    outf[(size_t)gm * 1024 + gn] = v;
                } else if (MODE == 0) {
                    v *= QSCALE;
                    int b = gm >> 11, s = gm & 2047;
                    int h = gn >> 6,  d = gn & 63;
                    out0[(((size_t)(b*NH_ + h)*S_ + s) << 6) + d] = f2bf(v);
                } else {
                    int b = gm >> 11, s = gm & 2047;
                    if (gn < C_) {
                        int h = gn >> 6, d = gn & 63;
                        out0[(((size_t)(b*NH_ + h)*S_ + s) << 6) + d] = f2bf(v);
                    } else {
                        int n2 = gn - C_;
                        int h = n2 >> 6, d = n2 & 63;
                        out1[((size_t)(b*NH_ + h)*HD_ + d)*S_ + s] = f2bf(v);
                    }
                }
            }
        }
    }
}

// ---- fused Q-proj + KV-proj: Q 512 tiles + KV 1024 = 1536, XCD-chunked 8x192 ----
__global__ __launch_bounds__(256, 3)
void proj_fused128(const unsigned short* __restrict__ xb, const unsigned short* __restrict__ Wqb,
                   const float* __restrict__ Wq_b,
                   const unsigned short* __restrict__ yb, const unsigned short* __restrict__ Wkvb,
                   const float* __restrict__ Wkv_b,
                   unsigned short* __restrict__ Qg, unsigned short* __restrict__ Kg,
                   unsigned short* __restrict__ Vt)
{
    __shared__ unsigned short shA[128*64];
    __shared__ unsigned short shB[128*64];
    int bid = blockIdx.x;
    int id = (bid & 7) * 192 + (bid >> 3);   // XCD c gets ids [c*192, c*192+192)
    if (id < 512) {
        gemm128_body<0>(xb, Wqb, Wq_b, Qg, nullptr, nullptr, id & 7, id >> 3, shA, shB);
    } else {
        int j = id - 512;
        gemm128_body<1>(yb, Wkvb, Wkv_b, Kg, Vt, nullptr, j & 15, j >> 4, shA, shB);
    }
}

// ---- standalone O-projection: 512 tiles, XCD-chunked 8x64 ----
__global__ __launch_bounds__(256, 3)
void gemm_oproj128(const unsigned short* __restrict__ A, const unsigned short* __restrict__ Bt,
                   const float* __restrict__ bias, float* __restrict__ outf)
{
    __shared__ unsigned short shA[128*64];
    __shared__ unsigned short shB[128*64];
    int id = ((blockIdx.x & 7) << 6) + (blockIdx.x >> 3);
    gemm128_body<2>(A, Bt, bias, nullptr, nullptr, outf, id & 7, id >> 3, shA, shB);
}

// ---------------- Flash attention, v3.3 (v3.2 + setprio around MFMA) ----------------
__global__ __launch_bounds__(256, 4)
void attn_kernel(const unsigned short* __restrict__ Qg, const unsigned short* __restrict__ Kg,
                 const unsigned short* __restrict__ Vt, const unsigned char* __restrict__ maskp,
                 unsigned short* __restrict__ att)
{
    __shared__ unsigned short Pl[64*72];
    __shared__ float Lbuf[4][64];
    __shared__ float Linv[64];
    int t = threadIdx.x, lane = t & 63, w = t >> 6;
    int quad = lane >> 4, l16 = lane & 15;
    int bh = blockIdx.x, b = bh >> 4, h = bh & 15;
    int qi = blockIdx.y;

    const unsigned short* kbase = Kg + ((size_t)bh*S_ + w*16 + l16)*HD_ + quad*8;
    const unsigned short* vbase = Vt + ((size_t)bh*HD_ + w*16 + l16)*S_ + quad*8;
    int kp_row = w*16 + quad*4;   // lane's k-row base within a tile
    const unsigned char* mbase = maskp + (size_t)b*S_ + kp_row;

    for (int half = 0; half < 2; ++half) {
        int qt = half ? (NT_ - 1 - qi) : qi;

        bf16x8 qf[4][2];
        #pragma unroll
        for (int m = 0; m < 4; ++m) {
            const unsigned short* qp = Qg + ((size_t)bh*S_ + qt*64 + m*16 + l16)*HD_;
            qf[m][0] = *reinterpret_cast<const bf16x8*>(qp + quad*8);
            qf[m][1] = *reinterpret_cast<const bf16x8*>(qp + 32 + quad*8);
        }
        f32x4 oacc[4] = {};
        float lsum[4] = {0.f, 0.f, 0.f, 0.f};

        bf16x8 kc0 = *reinterpret_cast<const bf16x8*>(kbase);
        bf16x8 kc1 = *reinterpret_cast<const bf16x8*>(kbase + 32);

        for (int kt = 0; kt <= qt; ++kt) {
            int ktn = (kt < qt) ? kt + 1 : kt;
            const unsigned short* kpn = kbase + (size_t)ktn*64*HD_;
            bf16x8 kn0 = *reinterpret_cast<const bf16x8*>(kpn);
            bf16x8 kn1 = *reinterpret_cast<const bf16x8*>(kpn + 32);
            const unsigned short* vp = vbase + kt*64;
            bf16x8 vc0 = *reinterpret_cast<const bf16x8*>(vp);
            bf16x8 vc1 = *reinterpret_cast<const bf16x8*>(vp + 32);

            unsigned m4 = *reinterpret_cast<const unsigned*>(mbase + kt*64);

            f32x4 sacc[4];
            __builtin_amdgcn_s_setprio(1);
            #pragma unroll
            for (int m = 0; m < 4; ++m) {
                sacc[m] = __builtin_amdgcn_mfma_f32_16x16x32_bf16(kc0, qf[m][0], f32x4{}, 0, 0, 0);
                sacc[m] = __builtin_amdgcn_mfma_f32_16x16x32_bf16(kc1, qf[m][1], sacc[m], 0, 0, 0);
            }
            __builtin_amdgcn_s_setprio(0);

            bool diag = (kt == qt);
            #pragma unroll
            for (int m = 0; m < 4; ++m) {
                float p[4];
                if (diag) {
                    #pragma unroll
                    for (int r = 0; r < 4; ++r) {
                        float s = sacc[m][r];
                        if (kp_row + r > m*16 + l16) s = -1e30f;
                        p[r] = __builtin_amdgcn_exp2f(s);
                    }
                } else {
                    #pragma unroll
                    for (int r = 0; r < 4; ++r)
                        p[r] = __builtin_amdgcn_exp2f(sacc[m][r]);
                }
                if (m4) {
                    #pragma unroll
                    for (int r = 0; r < 4; ++r)
                        if ((m4 >> (8*r)) & 0xFFu) p[r] = 0.f;
                }
                lsum[m] += (p[0] + p[1]) + (p[2] + p[3]);
                unsigned a01 = __builtin_amdgcn_perm(__float_as_uint(p[1]), __float_as_uint(p[0]), 0x07060302u);
                unsigned a23 = __builtin_amdgcn_perm(__float_as_uint(p[3]), __float_as_uint(p[2]), 0x07060302u);
                *reinterpret_cast<uint2*>(&Pl[(m*16 + l16)*72 + w*16 + quad*4]) = make_uint2(a01, a23);
            }
            __syncthreads();
            __builtin_amdgcn_s_setprio(1);
            #pragma unroll
            for (int m = 0; m < 4; ++m) {
                bf16x8 pf0 = *reinterpret_cast<const bf16x8*>(&Pl[(m*16 + l16)*72 + quad*8]);
                bf16x8 pf1 = *reinterpret_cast<const bf16x8*>(&Pl[(m*16 + l16)*72 + 32 + quad*8]);
                oacc[m] = __builtin_amdgcn_mfma_f32_16x16x32_bf16(pf0, vc0, oacc[m], 0, 0, 0);
                oacc[m] = __builtin_amdgcn_mfma_f32_16x16x32_bf16(pf1, vc1, oacc[m], 0, 0, 0);
            }
            __builtin_amdgcn_s_setprio(0);
            __syncthreads();
            kc0 = kn0; kc1 = kn1;
        }

        #pragma unroll
        for (int m = 0; m < 4; ++m) {
            lsum[m] += __shfl_xor(lsum[m], 16, 64);
            lsum[m] += __shfl_xor(lsum[m], 32, 64);
            Lbuf[w][m*16 + l16] = lsum[m];
        }
        __syncthreads();
        int q64 = t & 63;
        Linv[q64] = 1.0f / (Lbuf[0][q64] + Lbuf[1][q64] + Lbuf[2][q64] + Lbuf[3][q64]);
        __syncthreads();
        #pragma unroll
        for (int m = 0; m < 4; ++m) {
            #pragma unroll
            for (int r = 0; r < 4; ++r) {
                float iv = Linv[m*16 + quad*4 + r];
                int q = qt*64 + m*16 + quad*4 + r;
                att[((size_t)(b*S_ + q))*C_ + h*HD_ + w*16 + l16] = f2bf(oacc[m][r] * iv);
            }
        }
        __syncthreads();
    }
}

// ---------------- launch ----------------
extern "C" void kernel_launch(void* const* d_in, const int* in_sizes, int n_in,
                              void* d_out, int out_size, void* d_ws, size_t ws_size,
                              hipStream_t stream) {
    const float* x     = (const float*)d_in[0];
    const float* y     = (const float*)d_in[1];
    const unsigned char* mask = (const unsigned char*)d_in[2];
    const float* Wq_w  = (const float*)d_in[3];
    const float* Wq_b  = (const float*)d_in[4];
    const float* Wkv_w = (const float*)d_in[5];
    const float* Wkv_b = (const float*)d_in[6];
    const float* Wo_w  = (const float*)d_in[7];
    const float* Wo_b  = (const float*)d_in[8];
    float* out = (float*)d_out;

    unsigned short* xb   = (unsigned short*)d_ws;
    unsigned short* yb   = xb   + (size_t)M_*C_;
    unsigned short* Wqb  = yb   + (size_t)M_*C_;
    unsigned short* Wkvb = Wqb  + (size_t)C_*C_;
    unsigned short* Wob  = Wkvb + (size_t)2*C_*C_;
    unsigned short* Qg   = Wob  + (size_t)C_*C_;
    unsigned short* Kg   = Qg   + (size_t)M_*C_;
    unsigned short* Vtg  = Kg   + (size_t)M_*C_;
    unsigned short* att  = xb;   // xb dead after Q proj

    cvt_all<<<10240, 256, 0, stream>>>((const float4*)x, (const float4*)y,
        (const float4*)Wq_w, (const float4*)Wkv_w, (const float4*)Wo_w,
        (uint4*)xb, (uint4*)yb, (uint4*)Wqb, (uint4*)Wkvb, (uint4*)Wob);

    proj_fused128<<<1536, 256, 0, stream>>>(xb, Wqb, Wq_b, yb, Wkvb, Wkv_b, Qg, Kg, Vtg);
    attn_kernel<<<dim3(B_*NH_, NT_/2), 256, 0, stream>>>(Qg, Kg, Vtg, mask, att);
    gemm_oproj128<<<512, 256, 0, stream>>>(att, Wob, Wo_b, out);
}